// Round 2
// baseline (173.621 us; speedup 1.0000x reference)
//
#include <hip/hip_runtime.h>
#include <hip/hip_bf16.h>
#include <stdint.h>

#define NN 4096
#define DD 256

typedef __attribute__((ext_vector_type(8))) short bf16x8;
typedef __attribute__((ext_vector_type(4))) float f32x4;

#define LOG2E 1.44269504088896f

typedef const unsigned int __attribute__((address_space(1)))* gu32p;
typedef unsigned int __attribute__((address_space(3)))* su32p;

__device__ __forceinline__ float fexp2(float x) { return __builtin_amdgcn_exp2f(x); }

// ---- kernel 1: L2-normalize rows of z_i, z_j and cast to bf16 ----
__global__ __launch_bounds__(256) void k_norm(const float* __restrict__ zi,
                                              const float* __restrict__ zj,
                                              __hip_bfloat16* __restrict__ oi,
                                              __hip_bfloat16* __restrict__ oj) {
  int gw = (blockIdx.x * 256 + threadIdx.x) >> 6;  // global wave id, one row each
  int lane = threadIdx.x & 63;
  const float* src = (gw < NN) ? zi : zj;
  __hip_bfloat16* dst = (gw < NN) ? oi : oj;
  int row = (gw < NN) ? gw : gw - NN;
  float4 v = ((const float4*)(src + (size_t)row * DD))[lane];
  float ss = v.x * v.x + v.y * v.y + v.z * v.z + v.w * v.w;
#pragma unroll
  for (int m = 1; m < 64; m <<= 1) ss += __shfl_xor(ss, m);
  float s = 1.0f / fmaxf(sqrtf(ss), 1e-12f);
  __hip_bfloat16* d = dst + (size_t)row * DD + lane * 4;
  d[0] = __float2bfloat16(v.x * s);
  d[1] = __float2bfloat16(v.y * s);
  d[2] = __float2bfloat16(v.z * s);
  d[3] = __float2bfloat16(v.w * s);
}

// ---- epilogue helper ----
// MODE 0: normal tile (dual row+col accumulation)
// MODE 1: ij diagonal tile (record diag S, no masking)
// MODE 2: symmetric-pass diagonal tile (mask to strict upper triangle c>r)
template <int MODE>
__device__ __forceinline__ void epilogue(
    const f32x4* acc, const float* labr, const float* __restrict__ labels,
    float* rA, float* rB, float* rC, float* rT,
    float (*colstat)[64], float* __restrict__ diag,
    int rowbase, int colbase, int wave, int fr, int kg, bool wantT) {
#pragma unroll
  for (int cf = 0; cf < 4; ++cf) {
    const int cg = colbase + cf * 16 + fr;
    const float labc = labels[cg];
    float cb5 = 0.f, cb = 0.f, cks = 0.f, ckk = 0.f;
#pragma unroll
    for (int reg = 0; reg < 4; ++reg) {
      const int rg = rowbase + wave * 16 + kg * 4 + reg;
      float S = acc[cf][reg];
      // sup-branch exp: b = exp(S/0.5 - 2); pure-branch exp = b^5
      float b = fexp2(fmaf(2.f * LOG2E, S, -2.f * LOG2E));
      float b2 = b * b, b4 = b2 * b2, b5 = b4 * b;
      float dl = labr[reg] - labc;
      float kk = fexp2(dl * dl * (-0.5f * LOG2E));  // exp(-0.5*dl^2)
      float ks = kk * S;
      if (MODE == 1) {
        if (cf == wave && fr == kg * 4 + reg) diag[rg] = S;
      }
      if (MODE == 2) {
        float m = (cg > rg) ? 1.f : 0.f;
        b5 *= m; b *= m; ks *= m; kk *= m;
      }
      rA[reg] += b5; rB[reg] += b; rC[reg] += ks; rT[reg] += kk;
      cb5 += b5; cb += b; cks += ks; ckk += kk;
    }
    // column sums: reduce over kg groups (lanes l, l^16, l^32, l^48)
    cb5 += __shfl_xor(cb5, 16); cb5 += __shfl_xor(cb5, 32);
    cb  += __shfl_xor(cb, 16);  cb  += __shfl_xor(cb, 32);
    cks += __shfl_xor(cks, 16); cks += __shfl_xor(cks, 32);
    ckk += __shfl_xor(ckk, 16); ckk += __shfl_xor(ckk, 32);
    if (kg == 0) {
      atomicAdd(&colstat[0][cf * 16 + fr], cb5);
      atomicAdd(&colstat[1][cf * 16 + fr], cb);
      atomicAdd(&colstat[2][cf * 16 + fr], cks);
      if (wantT) atomicAdd(&colstat[3][cf * 16 + fr], ckk);
    }
  }
}

// ---- kernel 2: fused similarity + reductions ----
// blockIdx.z: 0 = ij (full; rows->A1/B1/C1, cols->A3/B3/C3, diag record)
//             1 = ii (upper triangle; rows+cols->A2/B2/C2, T)
//             2 = jj (upper triangle; rows+cols->A4/B4/C4)
// stats layout [13][NN]: 0..3 A1..A4, 4..7 B1..B4, 8..11 C1..C4, 12 T(pairs)
__global__ __launch_bounds__(256, 4) void k_main(
    const __hip_bfloat16* __restrict__ zin, const __hip_bfloat16* __restrict__ zjn,
    const float* __restrict__ labels,
    float* __restrict__ stats, float* __restrict__ diag) {
  __shared__ short lB[64 * 256];     // 32KB, linear row-major, swizzled content
  __shared__ float colstat[4][64];   // 1KB per-tile column stats

  const int cc = blockIdx.x;         // colchunk 0..3 (1024 cols each)
  const int by = blockIdx.y;         // rowblock 0..63 (64 rows each)
  const int combo = blockIdx.z;
  const int dt = by - cc * 16;       // tile index holding the diagonal (may be out of range)
  int tstart = 0;
  if (combo != 0) {
    tstart = dt > 0 ? dt : 0;
    if (tstart >= 16) return;        // block entirely below diagonal
  }

  const __hip_bfloat16* Ap = (combo == 2) ? zjn : zin;
  const __hip_bfloat16* Bp = (combo == 1) ? zin : zjn;
  const int rS0 = (combo == 0) ? 0 : (combo == 1 ? 1 : 3);
  const int cS0 = (combo == 0) ? 2 : (combo == 1 ? 1 : 3);
  const bool wantT = (combo == 1);

  const int tid = threadIdx.x;
  const int lane = tid & 63;
  const int wave = tid >> 6;
  const int fr = lane & 15;          // frag row (A) / col (B)
  const int kg = lane >> 4;          // k-group 0..3
  const int rowbase = by * 64;

  ((float*)colstat)[tid] = 0.f;      // 256 entries, 256 threads

  // A fragments live in registers for all 16 tiles (32 VGPRs)
  bf16x8 a[8];
  const int arow = rowbase + wave * 16 + fr;
#pragma unroll
  for (int k = 0; k < 8; ++k)
    a[k] = *(const bf16x8*)(Ap + (size_t)arow * DD + k * 32 + kg * 8);

  float labr[4];
#pragma unroll
  for (int reg = 0; reg < 4; ++reg)
    labr[reg] = labels[rowbase + wave * 16 + kg * 4 + reg];

  float rA[4] = {0, 0, 0, 0}, rB[4] = {0, 0, 0, 0};
  float rC[4] = {0, 0, 0, 0}, rT[4] = {0, 0, 0, 0};

  // Swizzled B-frag base address (bytes). Logical read for (row=cf*16+fr, k, kg):
  //   byte = (row*512 + k*64 + kg*16) ^ ((row&7)<<4)  ==  (P0 ^ (k<<6)) + cf*8192
  const int frb = (fr >> 2) & 1;
  const int P0 = fr * 512 + ((kg ^ (fr & 3)) << 4) + (frb << 6);
  char* lBc = (char*)lB;

  for (int t = tstart; t < 16; ++t) {
    const int colbase = cc * 1024 + t * 64;
    // stage B tile (64 rows x 256 bf16 = 32KB) via global_load_lds,
    // source pre-swizzled: LDS chunk f holds global chunk f ^ ((f>>5)&7)
    const char* Bt = (const char*)Bp + (size_t)colbase * 512;
#pragma unroll
    for (int j = 0; j < 8; ++j) {
      int f = tid + 256 * j;
      int g = f ^ ((f >> 5) & 7);
      __builtin_amdgcn_global_load_lds(
          (gu32p)(const void*)(Bt + (size_t)g * 16),
          (su32p)(void*)(lBc + (wave * 64 + 256 * j) * 16),
          16, 0, 0);
    }
    __syncthreads();  // DMA drained; prev colstat flush/zero visible

    f32x4 acc[4] = {{0, 0, 0, 0}, {0, 0, 0, 0}, {0, 0, 0, 0}, {0, 0, 0, 0}};
#pragma unroll
    for (int k = 0; k < 8; ++k) {
      const char* bbase = lBc + (P0 ^ (k << 6));
#pragma unroll
      for (int cf = 0; cf < 4; ++cf) {
        bf16x8 bv = *(const bf16x8*)(bbase + cf * 8192);
        acc[cf] = __builtin_amdgcn_mfma_f32_16x16x32_bf16(a[k], bv, acc[cf], 0, 0, 0);
      }
    }

    if (t == dt) {
      if (combo == 0)
        epilogue<1>(acc, labr, labels, rA, rB, rC, rT, colstat, diag,
                    rowbase, colbase, wave, fr, kg, wantT);
      else
        epilogue<2>(acc, labr, labels, rA, rB, rC, rT, colstat, diag,
                    rowbase, colbase, wave, fr, kg, wantT);
    } else {
      epilogue<0>(acc, labr, labels, rA, rB, rC, rT, colstat, diag,
                  rowbase, colbase, wave, fr, kg, wantT);
    }

    __syncthreads();  // all colstat ds_adds complete
    {
      int s = tid >> 6, c = tid & 63;
      float v = colstat[s][c];
      colstat[s][c] = 0.f;
      if (s < 3) atomicAdd(&stats[(cS0 + s * 4) * NN + colbase + c], v);
      else if (wantT) atomicAdd(&stats[12 * NN + colbase + c], v);
    }
    // no barrier needed: next ds_adds are ordered behind next tile's __syncthreads
  }

  // flush row stats (accumulated across tiles in registers)
#pragma unroll
  for (int reg = 0; reg < 4; ++reg) {
    float va = rA[reg], vb = rB[reg], vc = rC[reg], vt = rT[reg];
#pragma unroll
    for (int m = 1; m < 16; m <<= 1) {
      va += __shfl_xor(va, m); vb += __shfl_xor(vb, m);
      vc += __shfl_xor(vc, m); vt += __shfl_xor(vt, m);
    }
    if (fr == 0) {
      int rg = rowbase + wave * 16 + kg * 4 + reg;
      atomicAdd(&stats[rS0 * NN + rg], va);
      atomicAdd(&stats[(rS0 + 4) * NN + rg], vb);
      atomicAdd(&stats[(rS0 + 8) * NN + rg], vc);
      if (wantT) atomicAdd(&stats[12 * NN + rg], vt);
    }
  }
}

// ---- kernel 3: finalize scalar loss ----
__global__ __launch_bounds__(256) void k_final(const float* __restrict__ stats,
                                               const float* __restrict__ diag,
                                               float* __restrict__ out) {
  __shared__ float red[2][4];
  float accP = 0.f, accS = 0.f;
  for (int i = threadIdx.x; i < NN; i += 256) {
    float A1 = stats[0 * NN + i], A2 = stats[1 * NN + i];
    float A3 = stats[2 * NN + i], A4 = stats[3 * NN + i];
    float B1 = stats[4 * NN + i], B2 = stats[5 * NN + i];
    float B3 = stats[6 * NN + i], B4 = stats[7 * NN + i];
    float C1 = stats[8 * NN + i], C2 = stats[9 * NN + i];
    float C3 = stats[10 * NN + i], C4 = stats[11 * NN + i];
    float T = stats[12 * NN + i];   // pair sums, diagonal excluded
    float d = diag[i];
    accP += logf(A1 + A2) + logf(A3 + A4) + 20.f - 20.f * d;
    float nrm = 2.f * T + 1.f;      // 2*(T+1) - 1
    float W = 2.f * (C1 + C2 + C3 + C4) / nrm;
    float lse = logf(B1 + B2) + logf(B3 + B4) + 4.f;
    accS += lse - W - 2.f * logf(nrm);
  }
#pragma unroll
  for (int m = 1; m < 64; m <<= 1) {
    accP += __shfl_xor(accP, m);
    accS += __shfl_xor(accS, m);
  }
  int wave = threadIdx.x >> 6, lane = threadIdx.x & 63;
  if (lane == 0) { red[0][wave] = accP; red[1][wave] = accS; }
  __syncthreads();
  if (threadIdx.x == 0) {
    float P = red[0][0] + red[0][1] + red[0][2] + red[0][3];
    float Ssum = red[1][0] + red[1][1] + red[1][2] + red[1][3];
    out[0] = 0.5f * (P / (float)NN) + 0.5f * (Ssum / (float)NN);
  }
}

extern "C" void kernel_launch(void* const* d_in, const int* in_sizes, int n_in,
                              void* d_out, int out_size, void* d_ws, size_t ws_size,
                              hipStream_t stream) {
  const float* zi = (const float*)d_in[0];
  const float* zj = (const float*)d_in[1];
  const float* labels = (const float*)d_in[2];
  float* out = (float*)d_out;

  char* ws = (char*)d_ws;
  __hip_bfloat16* zinH = (__hip_bfloat16*)ws;                          // 2 MB
  __hip_bfloat16* zjnH = (__hip_bfloat16*)(ws + (size_t)NN * DD * 2);  // 2 MB
  float* stats = (float*)(ws + (size_t)NN * DD * 4);                   // 13*NN floats
  float* diag = stats + 13 * NN;                                       // NN floats

  hipMemsetAsync(stats, 0, 13 * NN * sizeof(float), stream);

  k_norm<<<2 * NN / 4, 256, 0, stream>>>(zi, zj, zinH, zjnH);

  dim3 grid(4, NN / 64, 3);
  k_main<<<grid, 256, 0, stream>>>(zinH, zjnH, labels, stats, diag);

  k_final<<<1, 256, 0, stream>>>(stats, diag, out);
}

// Round 3
// 77.078 us; speedup vs baseline: 2.2525x; 2.2525x over previous
//
#include <hip/hip_runtime.h>
#include <hip/hip_bf16.h>

#define NN 4096
#define DD 256

typedef __attribute__((ext_vector_type(8))) short bf16x8;
typedef __attribute__((ext_vector_type(4))) float f32x4;

#define LOG2E 1.44269504088896f

typedef const unsigned int __attribute__((address_space(1)))* gu32p;
typedef unsigned int __attribute__((address_space(3)))* su32p;

__device__ __forceinline__ float fexp2(float x) { return __builtin_amdgcn_exp2f(x); }

// ---- kernel 1: L2-normalize rows of z_i, z_j and cast to bf16 ----
__global__ __launch_bounds__(256) void k_norm(const float* __restrict__ zi,
                                              const float* __restrict__ zj,
                                              __hip_bfloat16* __restrict__ oi,
                                              __hip_bfloat16* __restrict__ oj) {
  int gw = (blockIdx.x * 256 + threadIdx.x) >> 6;  // one row per wave
  int lane = threadIdx.x & 63;
  const float* src = (gw < NN) ? zi : zj;
  __hip_bfloat16* dst = (gw < NN) ? oi : oj;
  int row = (gw < NN) ? gw : gw - NN;
  float4 v = ((const float4*)(src + (size_t)row * DD))[lane];
  float ss = v.x * v.x + v.y * v.y + v.z * v.z + v.w * v.w;
#pragma unroll
  for (int m = 1; m < 64; m <<= 1) ss += __shfl_xor(ss, m);
  float s = 1.0f / fmaxf(sqrtf(ss), 1e-12f);
  __hip_bfloat16* d = dst + (size_t)row * DD + lane * 4;
  d[0] = __float2bfloat16(v.x * s);
  d[1] = __float2bfloat16(v.y * s);
  d[2] = __float2bfloat16(v.z * s);
  d[3] = __float2bfloat16(v.w * s);
}

// ---- epilogue: convert 128x64 tile of S into per-row stat contributions ----
// MODE 0: normal tile  MODE 1: ij diag tile (record diag S)  MODE 2: ii/jj diag tile (mask rg==cg)
template <int MODE>
__device__ __forceinline__ void epi(
    const f32x4 acc[2][4], const float labr[2][4], const float* __restrict__ labels,
    float rA[2][4], float rB[2][4], float rC[2][4], float rT[2][4],
    float* __restrict__ diag, int rowbase, int colbase, int wave, int fr, int kg) {
#pragma unroll
  for (int cf = 0; cf < 4; ++cf) {
    const int cg = colbase + cf * 16 + fr;
    const float labc = labels[cg];
#pragma unroll
    for (int sub = 0; sub < 2; ++sub) {
#pragma unroll
      for (int reg = 0; reg < 4; ++reg) {
        float S = acc[sub][cf][reg];
        // b = exp(S/0.5 - 2); pure-branch exp(S/0.1 - 10) = b^5
        float b = fexp2(fmaf(2.f * LOG2E, S, -2.f * LOG2E));
        float b2 = b * b;
        float b5 = b2 * b2 * b;
        float dl = labr[sub][reg] - labc;
        float kk = fexp2(dl * dl * (-0.5f * LOG2E));  // exp(-0.5*dl^2), GAMMA=0.5
        float ks = kk * S;
        if (MODE != 0) {
          const int rg = rowbase + wave * 32 + sub * 16 + kg * 4 + reg;
          if (MODE == 1) {
            if (rg == cg) diag[rg] = S;
          }
          if (MODE == 2) {
            if (rg == cg) { b = 0.f; b5 = 0.f; ks = 0.f; kk = 0.f; }
          }
        }
        rA[sub][reg] += b5;
        rB[sub][reg] += b;
        rC[sub][reg] += ks;
        rT[sub][reg] += kk;
      }
    }
  }
}

// ---- kernel 2: fused similarity passes, row-stats only, no atomics ----
// combo (blockIdx.z): 0 ij (S=zin.zjn^T, rows=i) -> planes 0/4/8, diag record
//                     1 ji (zjn.zin^T, rows=j)   -> planes 2/6/10
//                     2 ii                        -> planes 1/5/9 + 12 (T), diag masked
//                     3 jj                        -> planes 3/7/11, diag masked
// part layout: part[cc][13][NN] floats, plain stores (disjoint per combo/cc/row)
__global__ __launch_bounds__(256, 2) void k_main(
    const __hip_bfloat16* __restrict__ zin, const __hip_bfloat16* __restrict__ zjn,
    const float* __restrict__ labels,
    float* __restrict__ part, float* __restrict__ diag) {
  __shared__ short lB[64 * 256];  // 32KB, linear, swizzled content

  const int cc = blockIdx.x;     // colchunk 0..3 (1024 cols)
  const int by = blockIdx.y;     // rowblock 0..31 (128 rows)
  const int combo = blockIdx.z;

  const __hip_bfloat16* Ap = (combo == 1 || combo == 3) ? zjn : zin;
  const __hip_bfloat16* Bp = (combo == 1 || combo == 2) ? zin : zjn;
  const int rS0 = (combo == 0) ? 0 : (combo == 1) ? 2 : (combo == 2) ? 1 : 3;
  const bool wantT = (combo == 2);

  const int tid = threadIdx.x;
  const int lane = tid & 63;
  const int wave = tid >> 6;
  const int fr = lane & 15;  // frag row (A) / col (B)
  const int kg = lane >> 4;  // k-group 0..3
  const int rowbase = by * 128;
  char* lBc = (char*)lB;

  // A fragments in registers: 2 sub-frags x 8 k-slices (64 VGPR)
  bf16x8 a[2][8];
#pragma unroll
  for (int sub = 0; sub < 2; ++sub) {
    const __hip_bfloat16* Ar =
        Ap + (size_t)(rowbase + wave * 32 + sub * 16 + fr) * DD + kg * 8;
#pragma unroll
    for (int k = 0; k < 8; ++k) a[sub][k] = *(const bf16x8*)(Ar + k * 32);
  }

  float labr[2][4];
#pragma unroll
  for (int sub = 0; sub < 2; ++sub)
#pragma unroll
    for (int reg = 0; reg < 4; ++reg)
      labr[sub][reg] = labels[rowbase + wave * 32 + sub * 16 + kg * 4 + reg];

  float rA[2][4] = {}, rB[2][4] = {}, rC[2][4] = {}, rT[2][4] = {};

  // Swizzled B read base: byte = (row*512 + k*64 + kg*16) ^ ((row&7)<<4)
  //                            = (P0 ^ (k<<6)) + cf*8192,  row = cf*16+fr
  const int frb = (fr >> 2) & 1;
  const int P0 = fr * 512 + ((kg ^ (fr & 3)) << 4) + (frb << 6);

  const int dt0 = by * 2 - cc * 16;  // first of 2 diag tiles (if in range)

  // stage B tile t (64 x 256 bf16 = 32KB), source pre-swizzled so that a
  // linear DMA write gives LDS chunk f = global chunk f ^ ((f>>5)&7)
#define STAGE(t)                                                              \
  {                                                                           \
    const char* Bt = (const char*)Bp + (size_t)(cc * 1024 + (t) * 64) * 512;  \
    _Pragma("unroll") for (int j = 0; j < 8; ++j) {                           \
      int f = tid + 256 * j;                                                  \
      int g = f ^ ((f >> 5) & 7);                                             \
      __builtin_amdgcn_global_load_lds(                                       \
          (gu32p)(const void*)(Bt + (size_t)g * 16),                          \
          (su32p)(void*)(lBc + (wave * 64 + 256 * j) * 16), 16, 0, 0);        \
    }                                                                         \
  }

  STAGE(0);

  for (int t = 0; t < 16; ++t) {
    __syncthreads();  // tile-t DMA drained (compiler emits vmcnt(0) before barrier)

    f32x4 acc[2][4];
#pragma unroll
    for (int s2 = 0; s2 < 2; ++s2)
#pragma unroll
      for (int cf = 0; cf < 4; ++cf) acc[s2][cf] = (f32x4){0.f, 0.f, 0.f, 0.f};

#pragma unroll
    for (int k = 0; k < 8; ++k) {
      const char* bbase = lBc + (P0 ^ (k << 6));
#pragma unroll
      for (int cf = 0; cf < 4; ++cf) {
        bf16x8 bv = *(const bf16x8*)(bbase + cf * 8192);
        acc[0][cf] = __builtin_amdgcn_mfma_f32_16x16x32_bf16(a[0][k], bv, acc[0][cf], 0, 0, 0);
        acc[1][cf] = __builtin_amdgcn_mfma_f32_16x16x32_bf16(a[1][k], bv, acc[1][cf], 0, 0, 0);
      }
    }

    __syncthreads();            // all waves done reading lB
    if (t < 15) STAGE(t + 1);   // next DMA overlaps epilogue VALU

    const int colbase = cc * 1024 + t * 64;
    if (combo != 1 && (unsigned)(t - dt0) < 2u) {
      if (combo == 0)
        epi<1>(acc, labr, labels, rA, rB, rC, rT, diag, rowbase, colbase, wave, fr, kg);
      else
        epi<2>(acc, labr, labels, rA, rB, rC, rT, diag, rowbase, colbase, wave, fr, kg);
    } else {
      epi<0>(acc, labr, labels, rA, rB, rC, rT, diag, rowbase, colbase, wave, fr, kg);
    }
  }

  // flush row stats: reduce over 16 fr-lanes, plain stores to this block's slice
  float* pc = part + (size_t)cc * 13 * NN;
#pragma unroll
  for (int sub = 0; sub < 2; ++sub)
#pragma unroll
    for (int reg = 0; reg < 4; ++reg) {
      float va = rA[sub][reg], vb = rB[sub][reg];
      float vc = rC[sub][reg], vt = rT[sub][reg];
#pragma unroll
      for (int m = 1; m < 16; m <<= 1) {
        va += __shfl_xor(va, m);
        vb += __shfl_xor(vb, m);
        vc += __shfl_xor(vc, m);
        vt += __shfl_xor(vt, m);
      }
      if (fr == 0) {
        int rg = rowbase + wave * 32 + sub * 16 + kg * 4 + reg;
        pc[rS0 * NN + rg] = va;
        pc[(rS0 + 4) * NN + rg] = vb;
        pc[(rS0 + 8) * NN + rg] = vc;
        if (wantT) pc[12 * NN + rg] = vt;
      }
    }
}

// ---- kernel 3: reduce partials over cc, finalize scalar loss ----
__global__ __launch_bounds__(256) void k_final(const float* __restrict__ part,
                                               const float* __restrict__ diag,
                                               float* __restrict__ out) {
  int i = blockIdx.x * 256 + threadIdx.x;
  float st[13];
#pragma unroll
  for (int p = 0; p < 13; ++p) {
    float s = 0.f;
#pragma unroll
    for (int c = 0; c < 4; ++c) s += part[((size_t)c * 13 + p) * NN + i];
    st[p] = s;
  }
  float d = diag[i];
  // planes: 0..3 = A(ij,ii,ji,jj), 4..7 = B, 8..11 = C, 12 = T (diag excl)
  float accP = logf(st[0] + st[1]) + logf(st[2] + st[3]) + 20.f - 20.f * d;
  float nrm = 2.f * st[12] + 1.f;
  float W = 2.f * (st[8] + st[9] + st[10] + st[11]) / nrm;
  float lse = logf(st[4] + st[5]) + logf(st[6] + st[7]) + 4.f;
  float accS = lse - W - 2.f * logf(nrm);
  float v = accP + accS;
#pragma unroll
  for (int m = 1; m < 64; m <<= 1) v += __shfl_xor(v, m);
  __shared__ float red[4];
  if ((threadIdx.x & 63) == 0) red[threadIdx.x >> 6] = v;
  __syncthreads();
  if (threadIdx.x == 0) {
    float s = red[0] + red[1] + red[2] + red[3];
    atomicAdd(out, 0.5f * s / (float)NN);
  }
}

extern "C" void kernel_launch(void* const* d_in, const int* in_sizes, int n_in,
                              void* d_out, int out_size, void* d_ws, size_t ws_size,
                              hipStream_t stream) {
  const float* zi = (const float*)d_in[0];
  const float* zj = (const float*)d_in[1];
  const float* labels = (const float*)d_in[2];
  float* out = (float*)d_out;

  char* ws = (char*)d_ws;
  __hip_bfloat16* zinH = (__hip_bfloat16*)ws;                          // 2 MB
  __hip_bfloat16* zjnH = (__hip_bfloat16*)(ws + (size_t)NN * DD * 2);  // 2 MB
  float* part = (float*)(ws + (size_t)NN * DD * 4);                    // 4*13*NN floats
  float* diag = part + 4 * 13 * NN;                                    // NN floats

  hipMemsetAsync(out, 0, sizeof(float), stream);

  k_norm<<<2 * NN / 4, 256, 0, stream>>>(zi, zj, zinH, zjnH);

  dim3 grid(4, NN / 128, 4);
  k_main<<<grid, 256, 0, stream>>>(zinH, zjnH, labels, part, diag);

  k_final<<<NN / 256, 256, 0, stream>>>(part, diag, out);
}